// Round 5
// baseline (35026.328 us; speedup 1.0000x reference)
//
#include <hip/hip_runtime.h>
#include <cstdint>
#include <cstddef>

// TransitionDown: FPS(8192 of 32768) + 16-NN + (Linear 64->128, BN, ReLU) + gather/maxpool
// R5: "contract-everywhere" hypothesis — XLA emits llvm.fmuladd for every product+add
// fusion (and DotDecomposer turns the K=3 dot into mul+reduce, also contracted).
// So: qq, pp, dot, FPS distance ALL use fma-ascending chains. Else identical to R4.

#define TD_N 32768
#define TD_M 8192

__device__ __forceinline__ float sq3_fma(float a, float b, float c) {
  // reduce(mul) with init 0, contracted: fma(c,c, fma(b,b, fma(a,a,0)))
  return fmaf(c, c, fmaf(b, b, __fmul_rn(a, a)));
}

// ---------------- K0: AoS -> SoA + |p|^2 (fma chain) ----------------
__global__ void k_soa(const float* __restrict__ p1, float* __restrict__ px,
                      float* __restrict__ py, float* __restrict__ pz,
                      float* __restrict__ pp) {
  int i = blockIdx.x * 256 + threadIdx.x;
  float a = p1[i * 3 + 0], b = p1[i * 3 + 1], c = p1[i * 3 + 2];
  px[i] = a; py[i] = b; pz[i] = c;
  pp[i] = sq3_fma(a, b, c);
}

// ---------------- K1: h = x@W + b, + per-block BN partial sums ----------------
__global__ __launch_bounds__(256) void k_mlp(const float* __restrict__ x,
                                             const float* __restrict__ W,
                                             const float* __restrict__ bias,
                                             float* __restrict__ h,
                                             float* __restrict__ part) {
  __shared__ float Wl[64 * 128];
  __shared__ float pl[4][2][128];
  int t = threadIdx.x;
#pragma unroll
  for (int i = 0; i < 8; ++i) {
    int f4 = t + i * 256;
    ((float4*)Wl)[f4] = ((const float4*)W)[f4];
  }
  __syncthreads();

  int rg = t >> 4;
  int ch = (t & 15) * 8;
  int row0 = blockIdx.x * 64 + rg * 4;

  float acc[4][8];
#pragma unroll
  for (int r = 0; r < 4; ++r)
#pragma unroll
    for (int c = 0; c < 8; ++c) acc[r][c] = 0.f;

  const float* xrow = x + (size_t)row0 * 64;
#pragma unroll 4
  for (int kc = 0; kc < 16; ++kc) {
    float xv[4][4];
#pragma unroll
    for (int r = 0; r < 4; ++r) {
      float4 t4 = *(const float4*)(xrow + r * 64 + kc * 4);
      xv[r][0] = t4.x; xv[r][1] = t4.y; xv[r][2] = t4.z; xv[r][3] = t4.w;
    }
#pragma unroll
    for (int kk = 0; kk < 4; ++kk) {
      int k = kc * 4 + kk;
      float4 wa = *(const float4*)&Wl[k * 128 + ch];
      float4 wb = *(const float4*)&Wl[k * 128 + ch + 4];
      float wv[8] = {wa.x, wa.y, wa.z, wa.w, wb.x, wb.y, wb.z, wb.w};
#pragma unroll
      for (int r = 0; r < 4; ++r)
#pragma unroll
        for (int c = 0; c < 8; ++c) acc[r][c] = fmaf(xv[r][kk], wv[c], acc[r][c]);
    }
  }

  float bv[8];
#pragma unroll
  for (int c = 0; c < 8; ++c) bv[c] = bias[ch + c];
  float s[8], q2[8];
#pragma unroll
  for (int c = 0; c < 8; ++c) { s[c] = 0.f; q2[c] = 0.f; }
#pragma unroll
  for (int r = 0; r < 4; ++r) {
    float hv[8];
#pragma unroll
    for (int c = 0; c < 8; ++c) hv[c] = acc[r][c] + bv[c];
    *(float4*)&h[(size_t)(row0 + r) * 128 + ch] = make_float4(hv[0], hv[1], hv[2], hv[3]);
    *(float4*)&h[(size_t)(row0 + r) * 128 + ch + 4] = make_float4(hv[4], hv[5], hv[6], hv[7]);
#pragma unroll
    for (int c = 0; c < 8; ++c) { s[c] += hv[c]; q2[c] = fmaf(hv[c], hv[c], q2[c]); }
  }
#pragma unroll
  for (int off = 16; off <= 32; off <<= 1) {
#pragma unroll
    for (int c = 0; c < 8; ++c) {
      s[c] += __shfl_xor(s[c], off);
      q2[c] += __shfl_xor(q2[c], off);
    }
  }
  int wv_ = t >> 6;
  if ((t & 63) < 16) {
#pragma unroll
    for (int c = 0; c < 8; ++c) { pl[wv_][0][ch + c] = s[c]; pl[wv_][1][ch + c] = q2[c]; }
  }
  __syncthreads();
  if (t < 128) {
    float S = 0.f, Q = 0.f;
#pragma unroll
    for (int w = 0; w < 4; ++w) { S += pl[w][0][t]; Q += pl[w][1][t]; }
    part[(size_t)blockIdx.x * 256 + t] = S;
    part[(size_t)blockIdx.x * 256 + 128 + t] = Q;
  }
}

// ---------------- K2: finalize BN -> scale/shift ----------------
__global__ void k_bn(const float* __restrict__ part, const float* __restrict__ gamma,
                     const float* __restrict__ beta, float* __restrict__ ss) {
  int t = threadIdx.x;  // 128
  float S = 0.f, Q = 0.f;
  for (int b = 0; b < 512; ++b) {
    S += part[(size_t)b * 256 + t];
    Q += part[(size_t)b * 256 + 128 + t];
  }
  float mean = S * (1.0f / 32768.0f);
  float var = Q * (1.0f / 32768.0f) - mean * mean;
  var = fmaxf(var, 0.0f);
  float inv = 1.0f / sqrtf(var + 1e-5f);
  float sc = gamma[t] * inv;
  ss[t] = sc;
  ss[128 + t] = beta[t] - mean * sc;
}

// ---------------- K3: FPS, single workgroup, fma-contracted distances ----------------
__global__ __launch_bounds__(512, 2) void k_fps(const float* __restrict__ px,
                                                const float* __restrict__ py,
                                                const float* __restrict__ pz,
                                                const float* __restrict__ p1,
                                                float* __restrict__ p2) {
  extern __shared__ float md[];  // [64][512]
  __shared__ float rv[8];
  __shared__ int ri[8];
  __shared__ float qs[3];
  int t = threadIdx.x;

  float cx[64], cy[64], cz[64];
#pragma unroll
  for (int j = 0; j < 64; ++j) {
    int idx = j * 512 + t;
    cx[j] = px[idx]; cy[j] = py[idx]; cz[j] = pz[idx];
    md[j * 512 + t] = 1e10f;
  }
  float qx = p1[0], qy = p1[1], qz = p1[2];
  if (t == 0) { p2[0] = qx; p2[1] = qy; p2[2] = qz; }
  __syncthreads();

  for (int it = 1; it < TD_M; ++it) {
    float best = -1.0f;
    int bj = 0;
#pragma unroll
    for (int j = 0; j < 64; ++j) {
      float dx = __fsub_rn(cx[j], qx);
      float dy = __fsub_rn(cy[j], qy);
      float dz = __fsub_rn(cz[j], qz);
      float d = fmaf(dz, dz, fmaf(dy, dy, __fmul_rn(dx, dx)));  // contracted chain
      float old = md[j * 512 + t];
      float nm = fminf(old, d);
      md[j * 512 + t] = nm;
      if (nm > best) { best = nm; bj = j; }  // strict > => lowest idx on ties
    }
    int bidx = bj * 512 + t;
#pragma unroll
    for (int off = 32; off; off >>= 1) {
      float ov = __shfl_xor(best, off);
      int oi = __shfl_xor(bidx, off);
      if (ov > best || (ov == best && oi < bidx)) { best = ov; bidx = oi; }
    }
    int wid = t >> 6;
    if ((t & 63) == 0) { rv[wid] = best; ri[wid] = bidx; }
    __syncthreads();
    if (t < 64) {
      float v = (t < 8) ? rv[t] : -1.0f;
      int ix = (t < 8) ? ri[t] : 0x7fffffff;
#pragma unroll
      for (int off = 4; off; off >>= 1) {
        float ov = __shfl_xor(v, off);
        int oi = __shfl_xor(ix, off);
        if (ov > v || (ov == v && oi < ix)) { v = ov; ix = oi; }
      }
      if (t == 0) {
        float wx = p1[(size_t)ix * 3 + 0];
        float wy = p1[(size_t)ix * 3 + 1];
        float wz = p1[(size_t)ix * 3 + 2];
        p2[(size_t)it * 3 + 0] = wx;
        p2[(size_t)it * 3 + 1] = wy;
        p2[(size_t)it * 3 + 2] = wz;
        qs[0] = wx; qs[1] = wy; qs[2] = wz;
      }
    }
    __syncthreads();
    qx = qs[0]; qy = qs[1]; qz = qs[2];
  }
}

// ---------------- K4: 16-NN — expanded f32, ALL-FMA chains (R5 change) ----------------
__device__ __forceinline__ unsigned long long shfl_xor_u64(unsigned long long v, int m) {
  unsigned lo = __shfl_xor((unsigned)v, m);
  unsigned hi = __shfl_xor((unsigned)(v >> 32), m);
  return ((unsigned long long)hi << 32) | lo;
}

__global__ __launch_bounds__(256) void k_knn(const float* __restrict__ px,
                                             const float* __restrict__ py,
                                             const float* __restrict__ pz,
                                             const float* __restrict__ pp,
                                             const float* __restrict__ p2,
                                             int* __restrict__ nb) {
  __shared__ unsigned long long mq[4][16][64];
  int wid = threadIdx.x >> 6, lane = threadIdx.x & 63;
  int q = blockIdx.x * 4 + wid;
  float qx = p2[(size_t)q * 3 + 0], qy = p2[(size_t)q * 3 + 1], qz = p2[(size_t)q * 3 + 2];
  float qq = sq3_fma(qx, qy, qz);  // fma chain (R5)

  unsigned long long sl[16];
#pragma unroll
  for (int s = 0; s < 16; ++s) sl[s] = ~0ULL;

#pragma unroll 2
  for (int c = 0; c < 512; ++c) {
    int i = c * 64 + lane;
    float X = px[i], Y = py[i], Z = pz[i], P = pp[i];
    float dot = fmaf(qz, Z, fmaf(qy, Y, __fmul_rn(qx, X)));       // fma-ascending
    float d2 = __fadd_rn(__fsub_rn(qq, __fadd_rn(dot, dot)), P);  // (qq - 2*dot) + pp
    unsigned u = __float_as_uint(d2);
    u ^= ((unsigned)(((int)u) >> 31)) | 0x80000000u;  // order-preserving float->uint
    unsigned long long key = ((unsigned long long)u << 32) | (unsigned)i;
#pragma unroll
    for (int s = 0; s < 16; ++s) {  // branchless sorted insert (asc)
      unsigned long long lo = key < sl[s] ? key : sl[s];
      unsigned long long hi = key < sl[s] ? sl[s] : key;
      sl[s] = lo;
      key = hi;
    }
  }
#pragma unroll
  for (int s = 0; s < 16; ++s) mq[wid][s][lane] = sl[s];
  int head = 0;
  for (int r = 0; r < 16; ++r) {
    int hh = head < 16 ? head : 15;
    unsigned long long kk = mq[wid][hh][lane];
    if (head >= 16) kk = ~0ULL;
    unsigned long long v = kk;
#pragma unroll
    for (int off = 32; off; off >>= 1) {
      unsigned long long o = shfl_xor_u64(v, off);
      if (o < v) v = o;
    }
    if (kk == v) head++;
    if (lane == 0) nb[(size_t)q * 16 + r] = (int)(v & 0xffffffffULL);
  }
}

// ---------------- K5: gather + affine + relu + maxpool ----------------
__global__ __launch_bounds__(256) void k_gather(const float* __restrict__ h,
                                                const float* __restrict__ ss,
                                                const int* __restrict__ nb,
                                                float* __restrict__ y) {
  int t = threadIdx.x;
  int q = blockIdx.x * 2 + (t >> 7);
  int ch = t & 127;
  float sc = ss[ch], sh = ss[128 + ch];
  float m = -3.4e38f;
#pragma unroll
  for (int k = 0; k < 16; ++k) {
    int n = nb[(size_t)q * 16 + k];
    float v = h[(size_t)n * 128 + ch];
    m = fmaxf(m, fmaf(v, sc, sh));
  }
  y[(size_t)q * 128 + ch] = fmaxf(m, 0.0f);
}

extern "C" void kernel_launch(void* const* d_in, const int* in_sizes, int n_in,
                              void* d_out, int out_size, void* d_ws, size_t ws_size,
                              hipStream_t stream) {
  (void)in_sizes; (void)n_in; (void)out_size; (void)ws_size;
  const float* x = (const float*)d_in[0];
  const float* p1 = (const float*)d_in[1];
  const float* W = (const float*)d_in[2];
  const float* bias = (const float*)d_in[3];
  const float* gamma = (const float*)d_in[4];
  const float* beta = (const float*)d_in[5];

  float* out = (float*)d_out;
  float* y = out;                    // (8192,128)
  float* p2 = out + 1048576;         // (8192,3)

  float* w = (float*)d_ws;
  float* h = w;                      // 4194304
  float* part = w + 4194304;         // 131072
  float* ss = w + 4325376;           // 256
  float* px = w + 4325632;           // 32768
  float* py = w + 4358400;
  float* pz = w + 4391168;
  float* pp = w + 4423936;
  int* nb = (int*)(w + 4456704);     // 8192*16

  hipFuncSetAttribute((const void*)k_fps, hipFuncAttributeMaxDynamicSharedMemorySize, 131072);

  k_soa<<<128, 256, 0, stream>>>(p1, px, py, pz, pp);
  k_mlp<<<512, 256, 0, stream>>>(x, W, bias, h, part);
  k_bn<<<1, 128, 0, stream>>>(part, gamma, beta, ss);
  k_fps<<<1, 512, 131072, stream>>>(px, py, pz, p1, p2);
  k_knn<<<2048, 256, 0, stream>>>(px, py, pz, pp, p2, nb);
  k_gather<<<4096, 256, 0, stream>>>(h, ss, nb, y);
}

// Round 6
// 26234.500 us; speedup vs baseline: 1.3351x; 1.3351x over previous
//
#include <hip/hip_runtime.h>
#include <cstdint>
#include <cstddef>

// TransitionDown: FPS(8192 of 32768) + 16-NN + (Linear 64->128, BN, ReLU) + gather/maxpool
// R6: FPS execution restructure (decision arithmetic UNCHANGED from R5-PASS):
//   1024 thr x 32 pts; min_d + x,y in VGPRs; z in LDS; launch_bounds(1024,4) -> no spill.
// FROZEN numerics (R5): distance = fmaf(dz,dz,fmaf(dy,dy,dx*dx)) with rn subs;
// kNN dot fma-asc, qq/pp fma chains; argmax/top-k tie-break = lowest index.

#define TD_N 32768
#define TD_M 8192
#define FPS_T 1024
#define FPS_J 32

__device__ __forceinline__ float sq3_fma(float a, float b, float c) {
  return fmaf(c, c, fmaf(b, b, __fmul_rn(a, a)));
}

// ---------------- K0: AoS -> SoA + |p|^2 (fma chain) ----------------
__global__ void k_soa(const float* __restrict__ p1, float* __restrict__ px,
                      float* __restrict__ py, float* __restrict__ pz,
                      float* __restrict__ pp) {
  int i = blockIdx.x * 256 + threadIdx.x;
  float a = p1[i * 3 + 0], b = p1[i * 3 + 1], c = p1[i * 3 + 2];
  px[i] = a; py[i] = b; pz[i] = c;
  pp[i] = sq3_fma(a, b, c);
}

// ---------------- K1: h = x@W + b, + per-block BN partial sums ----------------
__global__ __launch_bounds__(256) void k_mlp(const float* __restrict__ x,
                                             const float* __restrict__ W,
                                             const float* __restrict__ bias,
                                             float* __restrict__ h,
                                             float* __restrict__ part) {
  __shared__ float Wl[64 * 128];
  __shared__ float pl[4][2][128];
  int t = threadIdx.x;
#pragma unroll
  for (int i = 0; i < 8; ++i) {
    int f4 = t + i * 256;
    ((float4*)Wl)[f4] = ((const float4*)W)[f4];
  }
  __syncthreads();

  int rg = t >> 4;
  int ch = (t & 15) * 8;
  int row0 = blockIdx.x * 64 + rg * 4;

  float acc[4][8];
#pragma unroll
  for (int r = 0; r < 4; ++r)
#pragma unroll
    for (int c = 0; c < 8; ++c) acc[r][c] = 0.f;

  const float* xrow = x + (size_t)row0 * 64;
#pragma unroll 4
  for (int kc = 0; kc < 16; ++kc) {
    float xv[4][4];
#pragma unroll
    for (int r = 0; r < 4; ++r) {
      float4 t4 = *(const float4*)(xrow + r * 64 + kc * 4);
      xv[r][0] = t4.x; xv[r][1] = t4.y; xv[r][2] = t4.z; xv[r][3] = t4.w;
    }
#pragma unroll
    for (int kk = 0; kk < 4; ++kk) {
      int k = kc * 4 + kk;
      float4 wa = *(const float4*)&Wl[k * 128 + ch];
      float4 wb = *(const float4*)&Wl[k * 128 + ch + 4];
      float wv[8] = {wa.x, wa.y, wa.z, wa.w, wb.x, wb.y, wb.z, wb.w};
#pragma unroll
      for (int r = 0; r < 4; ++r)
#pragma unroll
        for (int c = 0; c < 8; ++c) acc[r][c] = fmaf(xv[r][kk], wv[c], acc[r][c]);
    }
  }

  float bv[8];
#pragma unroll
  for (int c = 0; c < 8; ++c) bv[c] = bias[ch + c];
  float s[8], q2[8];
#pragma unroll
  for (int c = 0; c < 8; ++c) { s[c] = 0.f; q2[c] = 0.f; }
#pragma unroll
  for (int r = 0; r < 4; ++r) {
    float hv[8];
#pragma unroll
    for (int c = 0; c < 8; ++c) hv[c] = acc[r][c] + bv[c];
    *(float4*)&h[(size_t)(row0 + r) * 128 + ch] = make_float4(hv[0], hv[1], hv[2], hv[3]);
    *(float4*)&h[(size_t)(row0 + r) * 128 + ch + 4] = make_float4(hv[4], hv[5], hv[6], hv[7]);
#pragma unroll
    for (int c = 0; c < 8; ++c) { s[c] += hv[c]; q2[c] = fmaf(hv[c], hv[c], q2[c]); }
  }
#pragma unroll
  for (int off = 16; off <= 32; off <<= 1) {
#pragma unroll
    for (int c = 0; c < 8; ++c) {
      s[c] += __shfl_xor(s[c], off);
      q2[c] += __shfl_xor(q2[c], off);
    }
  }
  int wv_ = t >> 6;
  if ((t & 63) < 16) {
#pragma unroll
    for (int c = 0; c < 8; ++c) { pl[wv_][0][ch + c] = s[c]; pl[wv_][1][ch + c] = q2[c]; }
  }
  __syncthreads();
  if (t < 128) {
    float S = 0.f, Q = 0.f;
#pragma unroll
    for (int w = 0; w < 4; ++w) { S += pl[w][0][t]; Q += pl[w][1][t]; }
    part[(size_t)blockIdx.x * 256 + t] = S;
    part[(size_t)blockIdx.x * 256 + 128 + t] = Q;
  }
}

// ---------------- K2: finalize BN -> scale/shift ----------------
__global__ void k_bn(const float* __restrict__ part, const float* __restrict__ gamma,
                     const float* __restrict__ beta, float* __restrict__ ss) {
  int t = threadIdx.x;  // 128
  float S = 0.f, Q = 0.f;
  for (int b = 0; b < 512; ++b) {
    S += part[(size_t)b * 256 + t];
    Q += part[(size_t)b * 256 + 128 + t];
  }
  float mean = S * (1.0f / 32768.0f);
  float var = Q * (1.0f / 32768.0f) - mean * mean;
  var = fmaxf(var, 0.0f);
  float inv = 1.0f / sqrtf(var + 1e-5f);
  float sc = gamma[t] * inv;
  ss[t] = sc;
  ss[128 + t] = beta[t] - mean * sc;
}

// ---------------- K3: FPS — 1024 thr x 32 pts, state in VGPRs, z in LDS ----------------
__global__ __launch_bounds__(1024, 4) void k_fps(const float* __restrict__ px,
                                                 const float* __restrict__ py,
                                                 const float* __restrict__ pz,
                                                 const float* __restrict__ p1,
                                                 float* __restrict__ p2) {
  extern __shared__ float lds[];          // z[32768] | rv[16] | ri[16] | qs[3]
  float* zs = lds;
  float* rv = lds + 32768;
  int* ri = (int*)(lds + 32768 + 16);
  float* qs = lds + 32768 + 32;
  int t = threadIdx.x;

  float cx[FPS_J], cy[FPS_J], md[FPS_J];
#pragma unroll
  for (int j = 0; j < FPS_J; ++j) {
    int idx = j * FPS_T + t;
    cx[j] = px[idx];
    cy[j] = py[idx];
    zs[idx] = pz[idx];
    md[j] = 1e10f;
  }
  float qx = p1[0], qy = p1[1], qz = p1[2];
  if (t == 0) { p2[0] = qx; p2[1] = qy; p2[2] = qz; }
  __syncthreads();

  for (int it = 1; it < TD_M; ++it) {
    float best = -1.0f;
    int bj = 0;
#pragma unroll
    for (int j = 0; j < FPS_J; ++j) {
      float dx = __fsub_rn(cx[j], qx);
      float dy = __fsub_rn(cy[j], qy);
      float dz = __fsub_rn(zs[j * FPS_T + t], qz);
      float d = fmaf(dz, dz, fmaf(dy, dy, __fmul_rn(dx, dx)));  // frozen chain
      float nm = fminf(md[j], d);
      md[j] = nm;
      if (nm > best) { best = nm; bj = j; }  // strict > => lowest j (lowest idx) on ties
    }
    int bidx = bj * FPS_T + t;
    // wave reduce: max value, tie -> min index
#pragma unroll
    for (int off = 32; off; off >>= 1) {
      float ov = __shfl_xor(best, off);
      int oi = __shfl_xor(bidx, off);
      if (ov > best || (ov == best && oi < bidx)) { best = ov; bidx = oi; }
    }
    int wid = t >> 6;
    if ((t & 63) == 0) { rv[wid] = best; ri[wid] = bidx; }
    __syncthreads();
    if (t < 64) {
      float v = (t < 16) ? rv[t] : -1.0f;
      int ix = (t < 16) ? ri[t] : 0x7fffffff;
#pragma unroll
      for (int off = 8; off; off >>= 1) {
        float ov = __shfl_xor(v, off);
        int oi = __shfl_xor(ix, off);
        if (ov > v || (ov == v && oi < ix)) { v = ov; ix = oi; }
      }
      if (t == 0) {
        float wx = p1[(size_t)ix * 3 + 0];
        float wy = p1[(size_t)ix * 3 + 1];
        float wz = p1[(size_t)ix * 3 + 2];
        p2[(size_t)it * 3 + 0] = wx;
        p2[(size_t)it * 3 + 1] = wy;
        p2[(size_t)it * 3 + 2] = wz;
        qs[0] = wx; qs[1] = wy; qs[2] = wz;
      }
    }
    __syncthreads();
    qx = qs[0]; qy = qs[1]; qz = qs[2];
  }
}

// ---------------- K4: 16-NN — expanded f32, all-FMA chains (frozen from R5) ----------------
__device__ __forceinline__ unsigned long long shfl_xor_u64(unsigned long long v, int m) {
  unsigned lo = __shfl_xor((unsigned)v, m);
  unsigned hi = __shfl_xor((unsigned)(v >> 32), m);
  return ((unsigned long long)hi << 32) | lo;
}

__global__ __launch_bounds__(256) void k_knn(const float* __restrict__ px,
                                             const float* __restrict__ py,
                                             const float* __restrict__ pz,
                                             const float* __restrict__ pp,
                                             const float* __restrict__ p2,
                                             int* __restrict__ nb) {
  __shared__ unsigned long long mq[4][16][64];
  int wid = threadIdx.x >> 6, lane = threadIdx.x & 63;
  int q = blockIdx.x * 4 + wid;
  float qx = p2[(size_t)q * 3 + 0], qy = p2[(size_t)q * 3 + 1], qz = p2[(size_t)q * 3 + 2];
  float qq = sq3_fma(qx, qy, qz);

  unsigned long long sl[16];
#pragma unroll
  for (int s = 0; s < 16; ++s) sl[s] = ~0ULL;

#pragma unroll 2
  for (int c = 0; c < 512; ++c) {
    int i = c * 64 + lane;
    float X = px[i], Y = py[i], Z = pz[i], P = pp[i];
    float dot = fmaf(qz, Z, fmaf(qy, Y, __fmul_rn(qx, X)));       // fma-ascending
    float d2 = __fadd_rn(__fsub_rn(qq, __fadd_rn(dot, dot)), P);  // (qq - 2*dot) + pp
    unsigned u = __float_as_uint(d2);
    u ^= ((unsigned)(((int)u) >> 31)) | 0x80000000u;
    unsigned long long key = ((unsigned long long)u << 32) | (unsigned)i;
#pragma unroll
    for (int s = 0; s < 16; ++s) {
      unsigned long long lo = key < sl[s] ? key : sl[s];
      unsigned long long hi = key < sl[s] ? sl[s] : key;
      sl[s] = lo;
      key = hi;
    }
  }
#pragma unroll
  for (int s = 0; s < 16; ++s) mq[wid][s][lane] = sl[s];
  int head = 0;
  for (int r = 0; r < 16; ++r) {
    int hh = head < 16 ? head : 15;
    unsigned long long kk = mq[wid][hh][lane];
    if (head >= 16) kk = ~0ULL;
    unsigned long long v = kk;
#pragma unroll
    for (int off = 32; off; off >>= 1) {
      unsigned long long o = shfl_xor_u64(v, off);
      if (o < v) v = o;
    }
    if (kk == v) head++;
    if (lane == 0) nb[(size_t)q * 16 + r] = (int)(v & 0xffffffffULL);
  }
}

// ---------------- K5: gather + affine + relu + maxpool ----------------
__global__ __launch_bounds__(256) void k_gather(const float* __restrict__ h,
                                                const float* __restrict__ ss,
                                                const int* __restrict__ nb,
                                                float* __restrict__ y) {
  int t = threadIdx.x;
  int q = blockIdx.x * 2 + (t >> 7);
  int ch = t & 127;
  float sc = ss[ch], sh = ss[128 + ch];
  float m = -3.4e38f;
#pragma unroll
  for (int k = 0; k < 16; ++k) {
    int n = nb[(size_t)q * 16 + k];
    float v = h[(size_t)n * 128 + ch];
    m = fmaxf(m, fmaf(v, sc, sh));
  }
  y[(size_t)q * 128 + ch] = fmaxf(m, 0.0f);
}

extern "C" void kernel_launch(void* const* d_in, const int* in_sizes, int n_in,
                              void* d_out, int out_size, void* d_ws, size_t ws_size,
                              hipStream_t stream) {
  (void)in_sizes; (void)n_in; (void)out_size; (void)ws_size;
  const float* x = (const float*)d_in[0];
  const float* p1 = (const float*)d_in[1];
  const float* W = (const float*)d_in[2];
  const float* bias = (const float*)d_in[3];
  const float* gamma = (const float*)d_in[4];
  const float* beta = (const float*)d_in[5];

  float* out = (float*)d_out;
  float* y = out;                    // (8192,128)
  float* p2 = out + 1048576;         // (8192,3)

  float* w = (float*)d_ws;
  float* h = w;                      // 4194304
  float* part = w + 4194304;         // 131072
  float* ss = w + 4325376;           // 256
  float* px = w + 4325632;           // 32768
  float* py = w + 4358400;
  float* pz = w + 4391168;
  float* pp = w + 4423936;
  int* nb = (int*)(w + 4456704);     // 8192*16

  // z[32768] + rv[16] + ri[16] + qs[3] floats
  const int fps_lds = (32768 + 16 + 16 + 4) * 4;
  hipFuncSetAttribute((const void*)k_fps, hipFuncAttributeMaxDynamicSharedMemorySize, fps_lds);

  k_soa<<<128, 256, 0, stream>>>(p1, px, py, pz, pp);
  k_mlp<<<512, 256, 0, stream>>>(x, W, bias, h, part);
  k_bn<<<1, 128, 0, stream>>>(part, gamma, beta, ss);
  k_fps<<<1, FPS_T, fps_lds, stream>>>(px, py, pz, p1, p2);
  k_knn<<<2048, 256, 0, stream>>>(px, py, pz, pp, p2, nb);
  k_gather<<<4096, 256, 0, stream>>>(h, ss, nb, y);
}